// Round 4
// baseline (376.044 us; speedup 1.0000x reference)
//
#include <hip/hip_runtime.h>
#include <hip/hip_bf16.h>
#include <math.h>

typedef unsigned int u32;
typedef unsigned short u16;
typedef __bf16 bf16x8 __attribute__((ext_vector_type(8)));
typedef float f32x4 __attribute__((ext_vector_type(4)));
typedef float f32x16 __attribute__((ext_vector_type(16)));
typedef u32 u32x4 __attribute__((ext_vector_type(4)));
typedef u32 u32x2 __attribute__((ext_vector_type(2)));
typedef u16 u16x4v __attribute__((ext_vector_type(4)));

#define T_DATA 500000
#define KNO    200          // T_no (kernel length)
#define SUB    20
#define E_NO   200
#define I_NO   50
#define NBAS   13
#define PI_F   3.14159265358979f
#define P_SZ   (T_DATA*SUB) // 10,000,000
#define MT_TOT (T_DATA/16)  // 31250
#define KK2    15           // conv v2 K-tiles: 15*16 = 240 taps window (j = r+207-kappa)
#define TCH2   1024
#define NCH2   ((T_DATA + TCH2 - 1)/TCH2)   // 489

__device__ __forceinline__ float bf2f(u16 v){
  union { u32 u; float f; } x; x.u = ((u32)v) << 16; return x.f;
}
__device__ __forceinline__ u16 f2bf(float f){
  union { float f; u32 u; } x; x.f = f;
  u32 u = x.u;
  return (u16)((u + 0x7FFFu + ((u >> 16) & 1u)) >> 16);
}
__device__ __forceinline__ u16 trunc_bf(float f){   // exact for 0.0/1.0 spikes
  union { float f; u32 u; } x; x.f = f;
  return (u16)(x.u >> 16);
}

// kernel-bank value k_{type,s}[j];  type: 0=e,1=i,2=spk,3=hist   (all params f32)
__device__ __forceinline__ float filt_val(int type, int s, int j,
    const float* Tau, const float* Del, const float* Wsyn,
    const float* Wspk, const float* Whist){
  if (type < 2){
    float tau = Tau[s*2+type];
    float del = Del[s*2+type];
    float w   = Wsyn[s*2+type];
    float t   = fmaxf((float)j - del, 0.0f);
    float tt  = t / (tau*tau);
    float v   = tt * expf(-tt) * (w*w);
    return (type == 1) ? -v : v;
  } else {
    const float* W = (type == 2) ? Wspk : Whist;
    float raw = 3.0f * logf((float)j + 1.0f);
    float acc = 0.0f;
#pragma unroll
    for (int b = 0; b < NBAS; b++){
      float d = raw - 0.5f*PI_F*(float)b;
      float bas = (d >= -PI_F && d <= PI_F) ? (0.5f*cosf(d) + 0.5f) : 0.0f;
      acc += W[s*NBAS + b] * bas;
    }
    return acc;
  }
}

// ---- K0a: write out_filters (vstack e,i,spk,hist) to tail of d_out (f32) ----
__global__ void k_filters(const float* Tau, const float* Del, const float* Wsyn,
                          const float* Wspk, const float* Whist, float* out){
  int r = blockIdx.x;              // 0..79
  int type = r / SUB, s = r % SUB;
  for (int j = threadIdx.x; j < KNO; j += blockDim.x)
    out[P_SZ + r*KNO + j] = filt_val(type, s, j, Tau, Del, Wsyn, Wspk, Whist);
}

// ---- K0b v2: conv A-fragments, 32-row Toeplitz for mfma_f32_32x32x16_bf16 ----
// A[r][kap] = ktap[r + 207 - kap] (0 outside [0,200)); kap = 16*kk + 8*(l>>5) + e
// layout: afrag2[(ts*KK2 + kk)*512 + l*8 + e], ts = type*SUB + s
__global__ void k_afrag2(const float* Tau, const float* Del, const float* Wsyn,
                         const float* Wspk, const float* Whist, u16* afrag2){
  int ts = blockIdx.x;             // 0..79
  int type = ts / SUB, s = ts % SUB;
  __shared__ float kf[KNO];
  for (int j = threadIdx.x; j < KNO; j += 64)
    kf[j] = filt_val(type, s, j, Tau, Del, Wsyn, Wspk, Whist);
  __syncthreads();
  int l = threadIdx.x;
  int r = l & 31, kg = l >> 5;
  for (int kk = 0; kk < KK2; kk++){
    u32 p[4];
#pragma unroll
    for (int h = 0; h < 4; h++){
      int kap0 = 16*kk + 8*kg + 2*h;
      int j0 = r + 207 - kap0;
      int j1 = j0 - 1;
      u16 lo = (j0 >= 0 && j0 < KNO) ? f2bf(kf[j0]) : (u16)0;
      u16 hi = (j1 >= 0 && j1 < KNO) ? f2bf(kf[j1]) : (u16)0;
      p[h] = (u32)lo | ((u32)hi << 16);
    }
    u32* dst = (u32*)(afrag2 + ((size_t)ts*KK2 + kk)*512 + l*8);
    dst[0]=p[0]; dst[1]=p[1]; dst[2]=p[2]; dst[3]=p[3];
  }
}

// ---- K0c: gather B-fragments (C_e^T, C_i^T, identity for Z), f32 -> bf16 ----
__global__ void k_bfrag(const float* Ce, const float* Ci, u16* bfrag){
  const int NE = 2*7*512, NI = 2*2*512, NZ = 2*1*512;
  for (int x = threadIdx.x + blockIdx.x*blockDim.x; x < NE+NI+NZ; x += blockDim.x*gridDim.x){
    int src, base, KT;
    if (x < NE){ src=0; base=x;       KT=7; }
    else if (x < NE+NI){ src=1; base=x-NE;    KT=2; }
    else {               src=2; base=x-NE-NI; KT=1; }
    int nt = base / (KT*512);
    int rem = base % (KT*512);
    int kt = rem / 512;
    int le = rem % 512;
    int l = le / 8, e = le % 8;
    int n = nt*16 + (l & 15);
    int k = kt*32 + (l >> 4)*8 + e;
    u16 v = 0;
    if (src == 0){ if (n < SUB && k < E_NO) v = trunc_bf(Ce[n*E_NO + k]); }
    else if (src == 1){ if (n < SUB && k < I_NO) v = trunc_bf(Ci[n*I_NO + k]); }
    else { if (n < SUB && k == n) v = trunc_bf(1.0f); }
    bfrag[x] = v;
  }
}

// ---- K1: gather via MFMA: dst[s][t] = sum_k src[t][k] * Bfrag[k][s] ----
template<int W, int KT>
__global__ __launch_bounds__(256) void k_gather(const float* __restrict__ src,
                                                const u16* __restrict__ bfrag,
                                                u16* __restrict__ dst){
  int wv = threadIdx.x >> 6, lane = threadIdx.x & 63;
  int mt = blockIdx.x*4 + wv;
  if (mt >= MT_TOT) return;
  int t0 = mt*16;
  int m = lane & 15, kg = lane >> 4;
  f32x4 acc0 = {0.f,0.f,0.f,0.f}, acc1 = {0.f,0.f,0.f,0.f};
  const size_t NW = (size_t)T_DATA * W;
#pragma unroll
  for (int kt = 0; kt < KT; kt++){
    size_t cs = (size_t)(t0 + m)*W + kt*32 + kg*8;
    union { bf16x8 v; u16 h[8]; } au;
    if (cs + 8 <= NW){
      u32 wbits[8];
      if (W == 50){                        // rows only 8B-aligned
        u32x2 a = *(const u32x2*)(src + cs);
        u32x2 b = *(const u32x2*)(src + cs + 2);
        u32x2 c = *(const u32x2*)(src + cs + 4);
        u32x2 d = *(const u32x2*)(src + cs + 6);
        wbits[0]=a[0]; wbits[1]=a[1]; wbits[2]=b[0]; wbits[3]=b[1];
        wbits[4]=c[0]; wbits[5]=c[1]; wbits[6]=d[0]; wbits[7]=d[1];
      } else {                             // 16B-aligned
        u32x4 a = *(const u32x4*)(src + cs);
        u32x4 b = *(const u32x4*)(src + cs + 4);
        wbits[0]=a[0]; wbits[1]=a[1]; wbits[2]=a[2]; wbits[3]=a[3];
        wbits[4]=b[0]; wbits[5]=b[1]; wbits[6]=b[2]; wbits[7]=b[3];
      }
#pragma unroll
      for (int e = 0; e < 8; e++) au.h[e] = (u16)(wbits[e] >> 16);
    } else {
#pragma unroll
      for (int e = 0; e < 8; e++){
        size_t idx = cs + e;
        au.h[e] = (idx < NW) ? trunc_bf(src[idx]) : (u16)0;
      }
    }
    bf16x8 b0 = *(const bf16x8*)(bfrag + kt*512 + lane*8);
    bf16x8 b1 = *(const bf16x8*)(bfrag + (KT + kt)*512 + lane*8);
    acc0 = __builtin_amdgcn_mfma_f32_16x16x32_bf16(au.v, b0, acc0, 0, 0, 0);
    acc1 = __builtin_amdgcn_mfma_f32_16x16x32_bf16(au.v, b1, acc1, 0, 0, 0);
  }
  int i0 = kg*4;
  {
    u32 lo = (u32)f2bf(acc0[0]) | ((u32)f2bf(acc0[1]) << 16);
    u32 hi = (u32)f2bf(acc0[2]) | ((u32)f2bf(acc0[3]) << 16);
    u32* d = (u32*)(dst + (size_t)m*T_DATA + t0 + i0);
    d[0] = lo; d[1] = hi;
  }
  if (m < SUB - 16){
    u32 lo = (u32)f2bf(acc1[0]) | ((u32)f2bf(acc1[1]) << 16);
    u32 hi = (u32)f2bf(acc1[2]) | ((u32)f2bf(acc1[3]) << 16);
    u32* d = (u32*)(dst + (size_t)(16 + m)*T_DATA + t0 + i0);
    d[0] = lo; d[1] = hi;
  }
}

// ---- K2 v2: grouped FIR via 32x32x16 MFMA, 1024-t chunks, fused epilogue ----
// out[t] = sum_j ktap[j] x[t-1-j];  t = t0c + 32n + r;  B[k][n] = x[t0c-208+32n+kap]
// A[r][kap] = ktap[r+207-kap]  (precomputed afrag2)
template<bool G>
__device__ __forceinline__ bf16x8 loadw2(const u16* __restrict__ row, long e0){
  if (!G) return *(const bf16x8*)(row + e0);
  union { bf16x8 v; u16 h[8]; } u;
#pragma unroll
  for (int e = 0; e < 8; e++){
    long i = e0 + e;
    u.h[e] = (i >= 0) ? row[i] : (u16)0;
  }
  return u.v;
}

template<bool G>
__device__ __forceinline__ void conv2_body(int wv, int lane, int c,
    const u16* __restrict__ xe, const u16* __restrict__ xi,
    const u16* __restrict__ zt, const u16* __restrict__ afrag2, u16* lsd)
{
  int n = lane & 31, half = lane >> 5;
  long base0 = (long)c*TCH2 - 208 + 32*n + 8*half;   // element offset within a row
  int ch0 = (wv < 4) ? wv*3 : 12 + (wv - 4)*2;
  int chn = (wv < 4) ? 3 : 2;
  int rot = n & ~3;

  for (int q = 0; q < chn; q++){
    int ch = ch0 + q;
    const u16* rE = xe + (size_t)ch*T_DATA;
    const u16* rI = xi + (size_t)ch*T_DATA;
    const u16* rZ = zt + (size_t)ch*T_DATA;
    const u16* aE = afrag2 + (size_t)((0*SUB + ch)*KK2)*512 + lane*8;
    const u16* aI = afrag2 + (size_t)((1*SUB + ch)*KK2)*512 + lane*8;
    const u16* aS = afrag2 + (size_t)((2*SUB + ch)*KK2)*512 + lane*8;
    const u16* aH = afrag2 + (size_t)((3*SUB + ch)*KK2)*512 + lane*8;
    f32x16 ash = {0.f};
    f32x16 asp = {0.f};
#pragma unroll
    for (int kk = 0; kk < KK2; kk++){
      long bo = base0 + 16*kk;
      bf16x8 be = loadw2<G>(rE, bo);
      bf16x8 bi = loadw2<G>(rI, bo);
      bf16x8 bz = loadw2<G>(rZ, bo);
      ash = __builtin_amdgcn_mfma_f32_32x32x16_bf16(*(const bf16x8*)(aE + kk*512), be, ash, 0,0,0);
      ash = __builtin_amdgcn_mfma_f32_32x32x16_bf16(*(const bf16x8*)(aI + kk*512), bi, ash, 0,0,0);
      ash = __builtin_amdgcn_mfma_f32_32x32x16_bf16(*(const bf16x8*)(aH + kk*512), bz, ash, 0,0,0);
      asp = __builtin_amdgcn_mfma_f32_32x32x16_bf16(*(const bf16x8*)(aS + kk*512), bz, asp, 0,0,0);
    }
    // write C tiles to LDS, rotate-swizzled: elem = 32n + ((r + (n&~3)) & 31)
#pragma unroll
    for (int qd = 0; qd < 4; qd++){
      int rb = 8*qd + 4*half;
      int elem = 32*n + ((rb + rot) & 31);
      u16x4v vsh, vsp;
#pragma unroll
      for (int i = 0; i < 4; i++){
        vsh[i] = f2bf(ash[4*qd + i]);
        vsp[i] = f2bf(asp[4*qd + i]);
      }
      *(u16x4v*)(lsd + (size_t)ch*TCH2 + elem)          = vsh;
      *(u16x4v*)(lsd + (size_t)(SUB + ch)*TCH2 + elem)  = vsp;
    }
  }
}

__global__ __launch_bounds__(512) void k_conv2(
    const u16* __restrict__ xe, const u16* __restrict__ xi,
    const u16* __restrict__ zt, const u16* __restrict__ afrag2,
    const float* __restrict__ Cden, const float* __restrict__ Theta,
    float* __restrict__ out)
{
  __shared__ __align__(16) u16 lsd[2*SUB*TCH2];   // 81,920 B exactly -> 2 blocks/CU

  int tid = threadIdx.x;
  int wv = tid >> 6, lane = tid & 63;

  // bijective XCD-aware chunk swizzle
  int bid = blockIdx.x;
  int xcd = bid & 7, sb = bid >> 3;
  const int q8 = NCH2 >> 3, r8 = NCH2 & 7;   // 61, 1
  int c = (xcd < r8 ? xcd*(q8+1) : r8*(q8+1) + (xcd-r8)*q8) + sb;

  if (c == 0) conv2_body<true >(wv, lane, c, xe, xi, zt, afrag2, lsd);
  else        conv2_body<false>(wv, lane, c, xe, xi, zt, afrag2, lsd);
  __syncthreads();

  // ---- epilogue: P = sigmoid(sh + theta + Cden @ spk); sh = syn + hist ----
#pragma unroll
  for (int k = 0; k < 2; k++){
    int t = tid + 512*k;
    int nn = t >> 5, rr = t & 31;
    int elem = 32*nn + ((rr + (nn & ~3)) & 31);
    float spv[SUB];
#pragma unroll
    for (int s = 0; s < SUB; s++) spv[s] = bf2f(lsd[(size_t)(SUB + s)*TCH2 + elem]);
    float res[SUB];
#pragma unroll
    for (int sp = 0; sp < SUB; sp++){
      float msum = bf2f(lsd[(size_t)sp*TCH2 + elem]) + Theta[sp];
#pragma unroll
      for (int u = 0; u < SUB; u++) msum += Cden[sp*SUB + u] * spv[u];
      res[sp] = 1.0f/(1.0f + expf(-msum));
    }
    long tg = (long)c*TCH2 + t;
    if (tg < T_DATA){
      float* d = out + (size_t)tg*SUB;
#pragma unroll
      for (int j = 0; j < 5; j++){
        float4 v; v.x = res[4*j]; v.y = res[4*j+1]; v.z = res[4*j+2]; v.w = res[4*j+3];
        *(float4*)(d + 4*j) = v;
      }
    }
  }
}

extern "C" void kernel_launch(void* const* d_in, const int* in_sizes, int n_in,
                              void* d_out, int out_size, void* d_ws, size_t ws_size,
                              hipStream_t stream){
  const float* S_e  = (const float*)d_in[0];
  const float* S_i  = (const float*)d_in[1];
  const float* Z    = (const float*)d_in[2];
  const float* Cden = (const float*)d_in[3];
  const float* C_e  = (const float*)d_in[4];
  const float* C_i  = (const float*)d_in[5];
  const float* Tau  = (const float*)d_in[6];
  const float* Del  = (const float*)d_in[7];
  const float* Wsyn = (const float*)d_in[8];
  const float* Wspk = (const float*)d_in[9];
  const float* Whist= (const float*)d_in[10];
  const float* Theta= (const float*)d_in[11];
  float* out = (float*)d_out;

  // workspace layout (bf16 elements)
  u16* xe     = (u16*)d_ws;
  u16* xi     = xe + (size_t)SUB*T_DATA;
  u16* zt     = xi + (size_t)SUB*T_DATA;
  u16* afrag2 = zt + (size_t)SUB*T_DATA;            // 80*15*512 = 614400
  u16* bfrag  = afrag2 + (size_t)4*SUB*KK2*512;     // 10240
  size_t need = ((size_t)3*SUB*T_DATA + (size_t)4*SUB*KK2*512 + 10240) * 2;
  if (ws_size < need) return;   // ~61.3 MB required

  k_filters<<<4*SUB, 64, 0, stream>>>(Tau, Del, Wsyn, Wspk, Whist, out);
  k_afrag2<<<4*SUB, 64, 0, stream>>>(Tau, Del, Wsyn, Wspk, Whist, afrag2);
  k_bfrag<<<4, 256, 0, stream>>>(C_e, C_i, bfrag);

  int gblk = (MT_TOT + 3)/4;
  k_gather<200,7><<<gblk, 256, 0, stream>>>(S_e, bfrag, xe);
  k_gather<50, 2><<<gblk, 256, 0, stream>>>(S_i, bfrag + 2*7*512, xi);
  k_gather<20, 1><<<gblk, 256, 0, stream>>>(Z,  bfrag + 2*7*512 + 2*2*512, zt);

  k_conv2<<<NCH2, 512, 0, stream>>>(xe, xi, zt, afrag2, Cden, Theta, out);
}

// Round 5
// 292.251 us; speedup vs baseline: 1.2867x; 1.2867x over previous
//
#include <hip/hip_runtime.h>
#include <hip/hip_bf16.h>
#include <math.h>

typedef unsigned int u32;
typedef unsigned short u16;
typedef __bf16 bf16x8 __attribute__((ext_vector_type(8)));
typedef float f32x4 __attribute__((ext_vector_type(4)));
typedef u32 u32x4 __attribute__((ext_vector_type(4)));
typedef u32 u32x2 __attribute__((ext_vector_type(2)));

#define T_DATA 500000
#define KNO    200          // T_no (kernel length)
#define SUB    20
#define E_NO   200
#define I_NO   50
#define NBAS   13
#define PI_F   3.14159265358979f
#define KKN    7            // conv K-tiles: 7*32 = 224 window
#define P_SZ   (T_DATA*SUB) // 10,000,000
#define MT_TOT (T_DATA/16)  // 31250
#define TCH    256
#define NCHUNKS_TOT ((T_DATA + TCH - 1)/TCH)   // 1954

__device__ __forceinline__ float bf2f(u16 v){
  union { u32 u; float f; } x; x.u = ((u32)v) << 16; return x.f;
}
__device__ __forceinline__ u16 f2bf(float f){
  union { float f; u32 u; } x; x.f = f;
  u32 u = x.u;
  return (u16)((u + 0x7FFFu + ((u >> 16) & 1u)) >> 16);
}
__device__ __forceinline__ u16 trunc_bf(float f){   // exact for 0.0/1.0 spikes
  union { float f; u32 u; } x; x.f = f;
  return (u16)(x.u >> 16);
}

// kernel-bank value k_{type,s}[j];  type: 0=e,1=i,2=spk,3=hist   (all params f32)
__device__ __forceinline__ float filt_val(int type, int s, int j,
    const float* Tau, const float* Del, const float* Wsyn,
    const float* Wspk, const float* Whist){
  if (type < 2){
    float tau = Tau[s*2+type];
    float del = Del[s*2+type];
    float w   = Wsyn[s*2+type];
    float t   = fmaxf((float)j - del, 0.0f);
    float tt  = t / (tau*tau);
    float v   = tt * expf(-tt) * (w*w);
    return (type == 1) ? -v : v;
  } else {
    const float* W = (type == 2) ? Wspk : Whist;
    float raw = 3.0f * logf((float)j + 1.0f);
    float acc = 0.0f;
#pragma unroll
    for (int b = 0; b < NBAS; b++){
      float d = raw - 0.5f*PI_F*(float)b;
      float bas = (d >= -PI_F && d <= PI_F) ? (0.5f*cosf(d) + 0.5f) : 0.0f;
      acc += W[s*NBAS + b] * bas;
    }
    return acc;
  }
}

// ---- K0a: write out_filters (vstack e,i,spk,hist) to tail of d_out (f32) ----
__global__ void k_filters(const float* Tau, const float* Del, const float* Wsyn,
                          const float* Wspk, const float* Whist, float* out){
  int r = blockIdx.x;              // 0..79
  int type = r / SUB, s = r % SUB;
  for (int j = threadIdx.x; j < KNO; j += blockDim.x)
    out[P_SZ + r*KNO + j] = filt_val(type, s, j, Tau, Del, Wsyn, Wspk, Whist);
}

// ---- K0b: conv A-fragments (kernel Toeplitz), ready-to-load per-lane 16B ----
// A_kk[m][u'] = k[off+m-1-u'], off = 200-32*kk ; layout [(type*SUB+s)*KKN+kk][lane*8]
__global__ void k_afrag(const float* Tau, const float* Del, const float* Wsyn,
                        const float* Wspk, const float* Whist, u16* afrag){
  int b = blockIdx.x;              // ((type*SUB)+s)*KKN + kk
  int kk = b % KKN;
  int ts = b / KKN;
  int type = ts / SUB, s = ts % SUB;
  __shared__ float kf[KNO];
  for (int j = threadIdx.x; j < KNO; j += 64)
    kf[j] = filt_val(type, s, j, Tau, Del, Wsyn, Wspk, Whist);
  __syncthreads();
  int l = threadIdx.x;
  int m = l & 15, kg = l >> 4;
  int off = 200 - 32*kk;
  u32 p[4];
#pragma unroll
  for (int h = 0; h < 4; h++){
    int u0 = kg*8 + 2*h;
    int i0 = off + m - 1 - u0;
    int i1 = i0 - 1;
    u16 lo = (i0 >= 0 && i0 < KNO) ? f2bf(kf[i0]) : (u16)0;
    u16 hi = (i1 >= 0 && i1 < KNO) ? f2bf(kf[i1]) : (u16)0;
    p[h] = (u32)lo | ((u32)hi << 16);
  }
  u32* dst = (u32*)(afrag + (size_t)b*512 + l*8);
  dst[0]=p[0]; dst[1]=p[1]; dst[2]=p[2]; dst[3]=p[3];
}

// ---- K0c: gather B-fragments (C_e^T, C_i^T, identity for Z), f32 -> bf16 ----
__global__ void k_bfrag(const float* Ce, const float* Ci, u16* bfrag){
  const int NE = 2*7*512, NI = 2*2*512, NZ = 2*1*512;
  for (int x = threadIdx.x + blockIdx.x*blockDim.x; x < NE+NI+NZ; x += blockDim.x*gridDim.x){
    int src, base, KT;
    if (x < NE){ src=0; base=x;       KT=7; }
    else if (x < NE+NI){ src=1; base=x-NE;    KT=2; }
    else {               src=2; base=x-NE-NI; KT=1; }
    int nt = base / (KT*512);
    int rem = base % (KT*512);
    int kt = rem / 512;
    int le = rem % 512;
    int l = le / 8, e = le % 8;
    int n = nt*16 + (l & 15);
    int k = kt*32 + (l >> 4)*8 + e;
    u16 v = 0;
    if (src == 0){ if (n < SUB && k < E_NO) v = trunc_bf(Ce[n*E_NO + k]); }
    else if (src == 1){ if (n < SUB && k < I_NO) v = trunc_bf(Ci[n*I_NO + k]); }
    else { if (n < SUB && k == n) v = trunc_bf(1.0f); }
    bfrag[x] = v;
  }
}

// ---- K1: gather via MFMA: dst[s][t] = sum_k src[t][k] * Bfrag[k][s] ----
template<int W, int KT>
__global__ __launch_bounds__(256) void k_gather(const float* __restrict__ src,
                                                const u16* __restrict__ bfrag,
                                                u16* __restrict__ dst){
  int wv = threadIdx.x >> 6, lane = threadIdx.x & 63;
  int mt = blockIdx.x*4 + wv;
  if (mt >= MT_TOT) return;
  int t0 = mt*16;
  int m = lane & 15, kg = lane >> 4;
  f32x4 acc0 = {0.f,0.f,0.f,0.f}, acc1 = {0.f,0.f,0.f,0.f};
  const size_t NW = (size_t)T_DATA * W;
#pragma unroll
  for (int kt = 0; kt < KT; kt++){
    size_t cs = (size_t)(t0 + m)*W + kt*32 + kg*8;
    union { bf16x8 v; u16 h[8]; } au;
    if (cs + 8 <= NW){
      u32 wbits[8];
      if (W == 50){                        // rows only 8B-aligned
        u32x2 a = *(const u32x2*)(src + cs);
        u32x2 b = *(const u32x2*)(src + cs + 2);
        u32x2 c = *(const u32x2*)(src + cs + 4);
        u32x2 d = *(const u32x2*)(src + cs + 6);
        wbits[0]=a[0]; wbits[1]=a[1]; wbits[2]=b[0]; wbits[3]=b[1];
        wbits[4]=c[0]; wbits[5]=c[1]; wbits[6]=d[0]; wbits[7]=d[1];
      } else {                             // 16B-aligned
        u32x4 a = *(const u32x4*)(src + cs);
        u32x4 b = *(const u32x4*)(src + cs + 4);
        wbits[0]=a[0]; wbits[1]=a[1]; wbits[2]=a[2]; wbits[3]=a[3];
        wbits[4]=b[0]; wbits[5]=b[1]; wbits[6]=b[2]; wbits[7]=b[3];
      }
#pragma unroll
      for (int e = 0; e < 8; e++) au.h[e] = (u16)(wbits[e] >> 16);
    } else {
#pragma unroll
      for (int e = 0; e < 8; e++){
        size_t idx = cs + e;
        au.h[e] = (idx < NW) ? trunc_bf(src[idx]) : (u16)0;
      }
    }
    bf16x8 b0 = *(const bf16x8*)(bfrag + kt*512 + lane*8);
    bf16x8 b1 = *(const bf16x8*)(bfrag + (KT + kt)*512 + lane*8);
    acc0 = __builtin_amdgcn_mfma_f32_16x16x32_bf16(au.v, b0, acc0, 0, 0, 0);
    acc1 = __builtin_amdgcn_mfma_f32_16x16x32_bf16(au.v, b1, acc1, 0, 0, 0);
  }
  int i0 = kg*4;   // C/D: t = 16*(lane&15) + 4*kg + reg ; channel = row block
  {
    u32 lo = (u32)f2bf(acc0[0]) | ((u32)f2bf(acc0[1]) << 16);
    u32 hi = (u32)f2bf(acc0[2]) | ((u32)f2bf(acc0[3]) << 16);
    u32* d = (u32*)(dst + (size_t)m*T_DATA + t0 + i0);
    d[0] = lo; d[1] = hi;
  }
  if (m < SUB - 16){
    u32 lo = (u32)f2bf(acc1[0]) | ((u32)f2bf(acc1[1]) << 16);
    u32 hi = (u32)f2bf(acc1[2]) | ((u32)f2bf(acc1[3]) << 16);
    u32* d = (u32*)(dst + (size_t)(16 + m)*T_DATA + t0 + i0);
    d[0] = lo; d[1] = hi;
  }
}

// ---- K2 v3: grouped FIR via MFMA, direct global B-loads, 8 waves/block ----
template<bool G>
__device__ __forceinline__ bf16x8 loadw(const u16* __restrict__ row, long base){
  if (!G) return *(const bf16x8*)(row + base);
  union { bf16x8 v; u16 h[8]; } u;
#pragma unroll
  for (int e = 0; e < 8; e++){
    long idx = base + e;
    u.h[e] = (idx >= 0 && idx < T_DATA) ? row[idx] : (u16)0;
  }
  return u.v;
}

// wv 0-3: e+i conv for 5 channels each -> syn rows [0,20)
// wv 4-7: z conv (spk+hist kernels) for 5 channels each -> rows [20,40),[40,60)
template<bool G>
__device__ __forceinline__ void conv_mfma(int wv, int lane, int c,
    const u16* __restrict__ xe, const u16* __restrict__ xi,
    const u16* __restrict__ zt, const u16* __restrict__ afrag, u16* rr)
{
  int m = lane & 15, kg = lane >> 4;
  int boffB = 16*m + 8*kg;
  int toff  = 16*m + 4*kg;
  long wbase = (long)c*TCH - 200 + boffB;

  if (wv < 4){
    int ch0 = wv*5;
    f32x4 acc[5];
#pragma unroll
    for (int q = 0; q < 5; q++){
      int ch = ch0 + q;
      const u16* rowE = xe + (size_t)ch*T_DATA;
      const u16* rowI = xi + (size_t)ch*T_DATA;
      const u16* ae = afrag + (size_t)((0*SUB + ch)*KKN)*512 + lane*8;
      const u16* ai = afrag + (size_t)((1*SUB + ch)*KKN)*512 + lane*8;
      f32x4 a = {0.f,0.f,0.f,0.f};
#pragma unroll
      for (int kk = 0; kk < KKN; kk++){
        bf16x8 be = loadw<G>(rowE, wbase + 32*kk);
        bf16x8 bi = loadw<G>(rowI, wbase + 32*kk);
        a = __builtin_amdgcn_mfma_f32_16x16x32_bf16(*(const bf16x8*)(ae + kk*512), be, a, 0,0,0);
        a = __builtin_amdgcn_mfma_f32_16x16x32_bf16(*(const bf16x8*)(ai + kk*512), bi, a, 0,0,0);
      }
      acc[q] = a;
    }
#pragma unroll
    for (int q = 0; q < 5; q++){
      int ch = ch0 + q;
      u32* d = (u32*)(rr + ch*TCH + toff);
      d[0] = (u32)f2bf(acc[q][0]) | ((u32)f2bf(acc[q][1]) << 16);
      d[1] = (u32)f2bf(acc[q][2]) | ((u32)f2bf(acc[q][3]) << 16);
    }
  } else {
    int ch0 = (wv - 4)*5;
    f32x4 as[5], ah[5];
#pragma unroll
    for (int q = 0; q < 5; q++){
      int ch = ch0 + q;
      const u16* rowZ = zt + (size_t)ch*T_DATA;
      const u16* a2 = afrag + (size_t)((2*SUB + ch)*KKN)*512 + lane*8;
      const u16* a3 = afrag + (size_t)((3*SUB + ch)*KKN)*512 + lane*8;
      f32x4 s = {0.f,0.f,0.f,0.f}, h = {0.f,0.f,0.f,0.f};
#pragma unroll
      for (int kk = 0; kk < KKN; kk++){
        bf16x8 bz = loadw<G>(rowZ, wbase + 32*kk);
        s = __builtin_amdgcn_mfma_f32_16x16x32_bf16(*(const bf16x8*)(a2 + kk*512), bz, s, 0,0,0);
        h = __builtin_amdgcn_mfma_f32_16x16x32_bf16(*(const bf16x8*)(a3 + kk*512), bz, h, 0,0,0);
      }
      as[q] = s; ah[q] = h;
    }
#pragma unroll
    for (int q = 0; q < 5; q++){
      int ch = ch0 + q;
      u32* d1 = (u32*)(rr + (SUB + ch)*TCH + toff);
      d1[0] = (u32)f2bf(as[q][0]) | ((u32)f2bf(as[q][1]) << 16);
      d1[1] = (u32)f2bf(as[q][2]) | ((u32)f2bf(as[q][3]) << 16);
      u32* d2 = (u32*)(rr + (2*SUB + ch)*TCH + toff);
      d2[0] = (u32)f2bf(ah[q][0]) | ((u32)f2bf(ah[q][1]) << 16);
      d2[1] = (u32)f2bf(ah[q][2]) | ((u32)f2bf(ah[q][3]) << 16);
    }
  }
}

__global__ __launch_bounds__(512, 4) void k_conv(
    const u16* __restrict__ xe, const u16* __restrict__ xi,
    const u16* __restrict__ zt, const u16* __restrict__ afrag,
    const float* __restrict__ Cden, const float* __restrict__ Theta,
    float* __restrict__ out)
{
  __shared__ __align__(16) u16 rr[3*SUB*TCH];    // 30,720 B (results; reused as P buf)
  __shared__ float lcden[SUB*SUB];
  __shared__ float lth[SUB];
  float* pbuf = (float*)rr;                      // [t*21 + sp], 21,504 B

  int tid = threadIdx.x;
  if (tid < SUB*SUB) lcden[tid] = Cden[tid];
  else if (tid < SUB*SUB + SUB) lth[tid - SUB*SUB] = Theta[tid - SUB*SUB];

  // bijective XCD-aware chunk swizzle: consecutive chunks share an XCD L2
  int bid = blockIdx.x;
  int xcd = bid & 7, sb = bid >> 3;
  const int q8 = NCHUNKS_TOT >> 3, r8 = NCHUNKS_TOT & 7;   // 244, 2
  int c = (xcd < r8 ? xcd*(q8+1) : r8*(q8+1) + (xcd-r8)*q8) + sb;

  int wv = tid >> 6, lane = tid & 63;
  if (c > 0 && c < NCHUNKS_TOT-1)
    conv_mfma<false>(wv, lane, c, xe, xi, zt, afrag, rr);
  else
    conv_mfma<true >(wv, lane, c, xe, xi, zt, afrag, rr);
  __syncthreads();

  // ---- epilogue: P = sigmoid(syn + theta + hist + Cden @ spk) ----
  int t = tid >> 1, h = tid & 1;
  float spkv[SUB];
#pragma unroll
  for (int s = 0; s < SUB; s++) spkv[s] = bf2f(rr[(SUB + s)*TCH + t]);
  float res[10];
#pragma unroll
  for (int j = 0; j < 10; j++){
    int sp = h*10 + j;
    float msum = bf2f(rr[sp*TCH + t]) + lth[sp] + bf2f(rr[(2*SUB + sp)*TCH + t]);
#pragma unroll
    for (int s = 0; s < SUB; s++) msum += lcden[sp*SUB + s] * spkv[s];
    res[j] = 1.0f/(1.0f + expf(-msum));
  }
  __syncthreads();               // all rr reads complete before overlay
#pragma unroll
  for (int j = 0; j < 10; j++) pbuf[t*21 + h*10 + j] = res[j];
  __syncthreads();

  // ---- fully coalesced float4 copy-out ----
  int t0c = c*TCH;
  int tv = min(TCH, T_DATA - t0c);
  int np4 = tv*SUB/4;            // 20 % 4 == 0 -> no row crossing
  for (int i = tid; i < np4; i += 512){
    int p = i*4;
    int tt = p/20, sp = p - tt*20;
    float4 v;
    v.x = pbuf[tt*21 + sp];   v.y = pbuf[tt*21 + sp+1];
    v.z = pbuf[tt*21 + sp+2]; v.w = pbuf[tt*21 + sp+3];
    *(float4*)(out + (size_t)t0c*SUB + p) = v;
  }
}

extern "C" void kernel_launch(void* const* d_in, const int* in_sizes, int n_in,
                              void* d_out, int out_size, void* d_ws, size_t ws_size,
                              hipStream_t stream){
  const float* S_e  = (const float*)d_in[0];
  const float* S_i  = (const float*)d_in[1];
  const float* Z    = (const float*)d_in[2];
  const float* Cden = (const float*)d_in[3];
  const float* C_e  = (const float*)d_in[4];
  const float* C_i  = (const float*)d_in[5];
  const float* Tau  = (const float*)d_in[6];
  const float* Del  = (const float*)d_in[7];
  const float* Wsyn = (const float*)d_in[8];
  const float* Wspk = (const float*)d_in[9];
  const float* Whist= (const float*)d_in[10];
  const float* Theta= (const float*)d_in[11];
  float* out = (float*)d_out;

  // workspace layout (bf16 elements) — identical to R3 passing round
  u16* xe    = (u16*)d_ws;
  u16* xi    = xe + (size_t)SUB*T_DATA;
  u16* zt    = xi + (size_t)SUB*T_DATA;
  u16* afrag = zt + (size_t)SUB*T_DATA;            // 4*20*7*512
  u16* bfrag = afrag + (size_t)4*SUB*KKN*512;      // 10240
  size_t need = ((size_t)3*SUB*T_DATA + (size_t)4*SUB*KKN*512 + 10240) * 2;
  if (ws_size < need) return;   // ~60.6 MB required

  k_filters<<<4*SUB, 64, 0, stream>>>(Tau, Del, Wsyn, Wspk, Whist, out);
  k_afrag<<<4*SUB*KKN, 64, 0, stream>>>(Tau, Del, Wsyn, Wspk, Whist, afrag);
  k_bfrag<<<4, 256, 0, stream>>>(C_e, C_i, bfrag);

  int gblk = (MT_TOT + 3)/4;
  k_gather<200,7><<<gblk, 256, 0, stream>>>(S_e, bfrag, xe);
  k_gather<50, 2><<<gblk, 256, 0, stream>>>(S_i, bfrag + 2*7*512, xi);
  k_gather<20, 1><<<gblk, 256, 0, stream>>>(Z,  bfrag + 2*7*512 + 2*2*512, zt);

  k_conv<<<NCHUNKS_TOT, 512, 0, stream>>>(xe, xi, zt, afrag, Cden, Theta, out);
}

// Round 6
// 274.697 us; speedup vs baseline: 1.3689x; 1.0639x over previous
//
#include <hip/hip_runtime.h>
#include <hip/hip_bf16.h>
#include <math.h>

typedef unsigned int u32;
typedef unsigned short u16;
typedef __bf16 bf16x8 __attribute__((ext_vector_type(8)));
typedef float f32x4 __attribute__((ext_vector_type(4)));
typedef u32 u32x4 __attribute__((ext_vector_type(4)));
typedef u32 u32x2 __attribute__((ext_vector_type(2)));

#define T_DATA 500000
#define KNO    200          // T_no (kernel length)
#define SUB    20
#define E_NO   200
#define I_NO   50
#define NBAS   13
#define PI_F   3.14159265358979f
#define KKN    7            // conv K-tiles: 7*32 = 224 window
#define P_SZ   (T_DATA*SUB) // 10,000,000
#define MT_TOT (T_DATA/16)  // 31250
#define TCH    256
#define NCHUNKS_TOT ((T_DATA + TCH - 1)/TCH)   // 1954
#define GBLK   ((MT_TOT + 3)/4)                // 7813

__device__ __forceinline__ float bf2f(u16 v){
  union { u32 u; float f; } x; x.u = ((u32)v) << 16; return x.f;
}
__device__ __forceinline__ u16 f2bf(float f){
  union { float f; u32 u; } x; x.f = f;
  u32 u = x.u;
  return (u16)((u + 0x7FFFu + ((u >> 16) & 1u)) >> 16);
}
__device__ __forceinline__ u16 trunc_bf(float f){   // exact for 0.0/1.0 spikes
  union { float f; u32 u; } x; x.f = f;
  return (u16)(x.u >> 16);
}
__device__ __forceinline__ u32 f2u(float f){
  union { float f; u32 u; } x; x.f = f; return x.u;
}

// kernel-bank value k_{type,s}[j];  type: 0=e,1=i,2=spk,3=hist   (all params f32)
__device__ __forceinline__ float filt_val(int type, int s, int j,
    const float* Tau, const float* Del, const float* Wsyn,
    const float* Wspk, const float* Whist){
  if (type < 2){
    float tau = Tau[s*2+type];
    float del = Del[s*2+type];
    float w   = Wsyn[s*2+type];
    float t   = fmaxf((float)j - del, 0.0f);
    float tt  = t / (tau*tau);
    float v   = tt * expf(-tt) * (w*w);
    return (type == 1) ? -v : v;
  } else {
    const float* W = (type == 2) ? Wspk : Whist;
    float raw = 3.0f * logf((float)j + 1.0f);
    float acc = 0.0f;
#pragma unroll
    for (int b = 0; b < NBAS; b++){
      float d = raw - 0.5f*PI_F*(float)b;
      float bas = (d >= -PI_F && d <= PI_F) ? (0.5f*cosf(d) + 0.5f) : 0.0f;
      acc += W[s*NBAS + b] * bas;
    }
    return acc;
  }
}

// ---- K0 merged setup: filters tail (blocks 0..79), afrag (80..639), bfrag (640..679) ----
__global__ void k_setup(const float* Tau, const float* Del, const float* Wsyn,
                        const float* Wspk, const float* Whist,
                        const float* Ce, const float* Ci,
                        float* out, u16* afrag, u16* bfrag){
  int bid = blockIdx.x;
  int tid = threadIdx.x;
  if (bid < 80){
    // out_filters (vstack e,i,spk,hist) to tail of d_out (f32)
    int r = bid, type = r / SUB, s = r % SUB;
    for (int j = tid; j < KNO; j += 64)
      out[P_SZ + r*KNO + j] = filt_val(type, s, j, Tau, Del, Wsyn, Wspk, Whist);
  } else if (bid < 80 + 4*SUB*KKN){
    // conv A-fragments: A_kk[m][u'] = k[off+m-1-u'], off = 200-32*kk
    int b = bid - 80;
    int kk = b % KKN;
    int ts = b / KKN;
    int type = ts / SUB, s = ts % SUB;
    __shared__ float kf[KNO];
    for (int j = tid; j < KNO; j += 64)
      kf[j] = filt_val(type, s, j, Tau, Del, Wsyn, Wspk, Whist);
    __syncthreads();
    int l = tid;
    int m = l & 15, kg = l >> 4;
    int off = 200 - 32*kk;
    u32 p[4];
#pragma unroll
    for (int h = 0; h < 4; h++){
      int u0 = kg*8 + 2*h;
      int i0 = off + m - 1 - u0;
      int i1 = i0 - 1;
      u16 lo = (i0 >= 0 && i0 < KNO) ? f2bf(kf[i0]) : (u16)0;
      u16 hi = (i1 >= 0 && i1 < KNO) ? f2bf(kf[i1]) : (u16)0;
      p[h] = (u32)lo | ((u32)hi << 16);
    }
    u32* dst = (u32*)(afrag + (size_t)b*512 + l*8);
    dst[0]=p[0]; dst[1]=p[1]; dst[2]=p[2]; dst[3]=p[3];
  } else {
    // gather B-fragments (C_e^T, C_i^T, identity for Z), f32 -> bf16
    const int NE = 2*7*512, NI = 2*2*512, NZ = 2*1*512;
    int b = bid - (80 + 4*SUB*KKN);               // 0..39
    for (int x = b*64 + tid; x < NE+NI+NZ; x += 40*64){
      int src, base, KT;
      if (x < NE){ src=0; base=x;       KT=7; }
      else if (x < NE+NI){ src=1; base=x-NE;    KT=2; }
      else {               src=2; base=x-NE-NI; KT=1; }
      int nt = base / (KT*512);
      int rem = base % (KT*512);
      int kt = rem / 512;
      int le = rem % 512;
      int l = le / 8, e = le % 8;
      int n = nt*16 + (l & 15);
      int k = kt*32 + (l >> 4)*8 + e;
      u16 v = 0;
      if (src == 0){ if (n < SUB && k < E_NO) v = trunc_bf(Ce[n*E_NO + k]); }
      else if (src == 1){ if (n < SUB && k < I_NO) v = trunc_bf(Ci[n*I_NO + k]); }
      else { if (n < SUB && k == n) v = trunc_bf(1.0f); }
      bfrag[x] = v;
    }
  }
}

// ---- K1: gather via MFMA with HOISTED loads: dst[s][t] = sum_k src[t][k]*B[k][s] ----
template<int W, int KT>
__device__ __forceinline__ void gather_body(int bid, const float* __restrict__ src,
                                            const u16* __restrict__ bfrag,
                                            u16* __restrict__ dst){
  int wv = threadIdx.x >> 6, lane = threadIdx.x & 63;
  int mt = bid*4 + wv;
  if (mt >= MT_TOT) return;
  int t0 = mt*16;
  int m = lane & 15, kg = lane >> 4;
  const size_t NW = (size_t)T_DATA * W;

  // hoist ALL row loads (KT*8 f32 per lane) -> up to 14 loads in flight
  u32 wb[KT][8];
#pragma unroll
  for (int kt = 0; kt < KT; kt++){
    size_t cs = (size_t)(t0 + m)*W + kt*32 + kg*8;
    if (cs + 8 <= NW){
      if (W == 50){                        // rows only 8B-aligned
        *(u32x2*)&wb[kt][0] = *(const u32x2*)(src + cs);
        *(u32x2*)&wb[kt][2] = *(const u32x2*)(src + cs + 2);
        *(u32x2*)&wb[kt][4] = *(const u32x2*)(src + cs + 4);
        *(u32x2*)&wb[kt][6] = *(const u32x2*)(src + cs + 6);
      } else {                             // 16B-aligned (W=200, W=20)
        *(u32x4*)&wb[kt][0] = *(const u32x4*)(src + cs);
        *(u32x4*)&wb[kt][4] = *(const u32x4*)(src + cs + 4);
      }
    } else {
#pragma unroll
      for (int e = 0; e < 8; e++){
        size_t idx = cs + e;
        wb[kt][e] = (idx < NW) ? f2u(src[idx]) : 0u;
      }
    }
  }

  f32x4 acc0 = {0.f,0.f,0.f,0.f}, acc1 = {0.f,0.f,0.f,0.f};
#pragma unroll
  for (int kt = 0; kt < KT; kt++){
    union { bf16x8 v; u16 h[8]; } au;
#pragma unroll
    for (int e = 0; e < 8; e++) au.h[e] = (u16)(wb[kt][e] >> 16);
    bf16x8 b0 = *(const bf16x8*)(bfrag + kt*512 + lane*8);
    bf16x8 b1 = *(const bf16x8*)(bfrag + (KT + kt)*512 + lane*8);
    acc0 = __builtin_amdgcn_mfma_f32_16x16x32_bf16(au.v, b0, acc0, 0, 0, 0);
    acc1 = __builtin_amdgcn_mfma_f32_16x16x32_bf16(au.v, b1, acc1, 0, 0, 0);
  }
  int i0 = kg*4;   // C/D: t = 16*(lane&15) + 4*kg + reg ; channel = row block
  {
    u32 lo = (u32)f2bf(acc0[0]) | ((u32)f2bf(acc0[1]) << 16);
    u32 hi = (u32)f2bf(acc0[2]) | ((u32)f2bf(acc0[3]) << 16);
    u32* d = (u32*)(dst + (size_t)m*T_DATA + t0 + i0);
    d[0] = lo; d[1] = hi;
  }
  if (m < SUB - 16){
    u32 lo = (u32)f2bf(acc1[0]) | ((u32)f2bf(acc1[1]) << 16);
    u32 hi = (u32)f2bf(acc1[2]) | ((u32)f2bf(acc1[3]) << 16);
    u32* d = (u32*)(dst + (size_t)(16 + m)*T_DATA + t0 + i0);
    d[0] = lo; d[1] = hi;
  }
}

__global__ __launch_bounds__(256, 4) void k_gather_all(
    const float* __restrict__ S_e, const float* __restrict__ S_i,
    const float* __restrict__ Z, const u16* __restrict__ bfrag,
    u16* __restrict__ xe, u16* __restrict__ xi, u16* __restrict__ zt){
  int bid = blockIdx.x;
  if (bid < GBLK)            gather_body<200,7>(bid,          S_e, bfrag,                       xe);
  else if (bid < 2*GBLK)     gather_body<50, 2>(bid - GBLK,   S_i, bfrag + 2*7*512,             xi);
  else                       gather_body<20, 1>(bid - 2*GBLK, Z,   bfrag + 2*7*512 + 2*2*512,   zt);
}

// ---- K2: grouped FIR via MFMA, direct global B-loads (hoisted), 8 waves/block ----
template<bool G>
__device__ __forceinline__ bf16x8 loadw(const u16* __restrict__ row, long base){
  if (!G) return *(const bf16x8*)(row + base);
  union { bf16x8 v; u16 h[8]; } u;
#pragma unroll
  for (int e = 0; e < 8; e++){
    long idx = base + e;
    u.h[e] = (idx >= 0 && idx < T_DATA) ? row[idx] : (u16)0;
  }
  return u.v;
}

// wv 0-3: e+i conv for 5 channels each -> syn rows [0,20)
// wv 4-7: z conv (spk+hist kernels) for 5 channels each -> rows [20,40),[40,60)
template<bool G>
__device__ __forceinline__ void conv_mfma(int wv, int lane, int c,
    const u16* __restrict__ xe, const u16* __restrict__ xi,
    const u16* __restrict__ zt, const u16* __restrict__ afrag, u16* rr)
{
  int m = lane & 15, kg = lane >> 4;
  int boffB = 16*m + 8*kg;
  int toff  = 16*m + 4*kg;
  long wbase = (long)c*TCH - 200 + boffB;

  if (wv < 4){
    int ch0 = wv*5;
    f32x4 acc[5];
#pragma unroll
    for (int q = 0; q < 5; q++){
      int ch = ch0 + q;
      const u16* rowE = xe + (size_t)ch*T_DATA;
      const u16* rowI = xi + (size_t)ch*T_DATA;
      const u16* ae = afrag + (size_t)((0*SUB + ch)*KKN)*512 + lane*8;
      const u16* ai = afrag + (size_t)((1*SUB + ch)*KKN)*512 + lane*8;
      // hoist the 14 B-loads (56 VGPR in flight); A-frags stay JIT (L2-resident)
      bf16x8 be[KKN], bi[KKN];
#pragma unroll
      for (int kk = 0; kk < KKN; kk++) be[kk] = loadw<G>(rowE, wbase + 32*kk);
#pragma unroll
      for (int kk = 0; kk < KKN; kk++) bi[kk] = loadw<G>(rowI, wbase + 32*kk);
      f32x4 a = {0.f,0.f,0.f,0.f};
#pragma unroll
      for (int kk = 0; kk < KKN; kk++){
        a = __builtin_amdgcn_mfma_f32_16x16x32_bf16(*(const bf16x8*)(ae + kk*512), be[kk], a, 0,0,0);
        a = __builtin_amdgcn_mfma_f32_16x16x32_bf16(*(const bf16x8*)(ai + kk*512), bi[kk], a, 0,0,0);
      }
      acc[q] = a;
    }
#pragma unroll
    for (int q = 0; q < 5; q++){
      int ch = ch0 + q;
      u32* d = (u32*)(rr + ch*TCH + toff);
      d[0] = (u32)f2bf(acc[q][0]) | ((u32)f2bf(acc[q][1]) << 16);
      d[1] = (u32)f2bf(acc[q][2]) | ((u32)f2bf(acc[q][3]) << 16);
    }
  } else {
    int ch0 = (wv - 4)*5;
    f32x4 as[5], ah[5];
#pragma unroll
    for (int q = 0; q < 5; q++){
      int ch = ch0 + q;
      const u16* rowZ = zt + (size_t)ch*T_DATA;
      const u16* a2 = afrag + (size_t)((2*SUB + ch)*KKN)*512 + lane*8;
      const u16* a3 = afrag + (size_t)((3*SUB + ch)*KKN)*512 + lane*8;
      bf16x8 bz[KKN];
#pragma unroll
      for (int kk = 0; kk < KKN; kk++) bz[kk] = loadw<G>(rowZ, wbase + 32*kk);
      f32x4 s = {0.f,0.f,0.f,0.f}, h = {0.f,0.f,0.f,0.f};
#pragma unroll
      for (int kk = 0; kk < KKN; kk++){
        s = __builtin_amdgcn_mfma_f32_16x16x32_bf16(*(const bf16x8*)(a2 + kk*512), bz[kk], s, 0,0,0);
        h = __builtin_amdgcn_mfma_f32_16x16x32_bf16(*(const bf16x8*)(a3 + kk*512), bz[kk], h, 0,0,0);
      }
      as[q] = s; ah[q] = h;
    }
#pragma unroll
    for (int q = 0; q < 5; q++){
      int ch = ch0 + q;
      u32* d1 = (u32*)(rr + (SUB + ch)*TCH + toff);
      d1[0] = (u32)f2bf(as[q][0]) | ((u32)f2bf(as[q][1]) << 16);
      d1[1] = (u32)f2bf(as[q][2]) | ((u32)f2bf(as[q][3]) << 16);
      u32* d2 = (u32*)(rr + (2*SUB + ch)*TCH + toff);
      d2[0] = (u32)f2bf(ah[q][0]) | ((u32)f2bf(ah[q][1]) << 16);
      d2[1] = (u32)f2bf(ah[q][2]) | ((u32)f2bf(ah[q][3]) << 16);
    }
  }
}

__global__ __launch_bounds__(512, 4) void k_conv(
    const u16* __restrict__ xe, const u16* __restrict__ xi,
    const u16* __restrict__ zt, const u16* __restrict__ afrag,
    const float* __restrict__ Cden, const float* __restrict__ Theta,
    float* __restrict__ out)
{
  __shared__ __align__(16) u16 rr[3*SUB*TCH];    // 30,720 B (results; reused as P buf)
  __shared__ float lcden[SUB*SUB];
  __shared__ float lth[SUB];
  float* pbuf = (float*)rr;                      // [t*21 + sp], 21,504 B

  int tid = threadIdx.x;
  if (tid < SUB*SUB) lcden[tid] = Cden[tid];
  else if (tid < SUB*SUB + SUB) lth[tid - SUB*SUB] = Theta[tid - SUB*SUB];

  // bijective XCD-aware chunk swizzle: consecutive chunks share an XCD L2
  int bid = blockIdx.x;
  int xcd = bid & 7, sb = bid >> 3;
  const int q8 = NCHUNKS_TOT >> 3, r8 = NCHUNKS_TOT & 7;   // 244, 2
  int c = (xcd < r8 ? xcd*(q8+1) : r8*(q8+1) + (xcd-r8)*q8) + sb;

  int wv = tid >> 6, lane = tid & 63;
  if (c > 0 && c < NCHUNKS_TOT-1)
    conv_mfma<false>(wv, lane, c, xe, xi, zt, afrag, rr);
  else
    conv_mfma<true >(wv, lane, c, xe, xi, zt, afrag, rr);
  __syncthreads();

  // ---- epilogue: P = sigmoid(syn + theta + hist + Cden @ spk) ----
  int t = tid >> 1, h = tid & 1;
  float spkv[SUB];
#pragma unroll
  for (int s = 0; s < SUB; s++) spkv[s] = bf2f(rr[(SUB + s)*TCH + t]);
  float res[10];
#pragma unroll
  for (int j = 0; j < 10; j++){
    int sp = h*10 + j;
    float msum = bf2f(rr[sp*TCH + t]) + lth[sp] + bf2f(rr[(2*SUB + sp)*TCH + t]);
#pragma unroll
    for (int s = 0; s < SUB; s++) msum += lcden[sp*SUB + s] * spkv[s];
    res[j] = 1.0f/(1.0f + expf(-msum));
  }
  __syncthreads();               // all rr reads complete before overlay
#pragma unroll
  for (int j = 0; j < 10; j++) pbuf[t*21 + h*10 + j] = res[j];
  __syncthreads();

  // ---- fully coalesced float4 copy-out ----
  int t0c = c*TCH;
  int tv = min(TCH, T_DATA - t0c);
  int np4 = tv*SUB/4;            // 20 % 4 == 0 -> no row crossing
  for (int i = tid; i < np4; i += 512){
    int p = i*4;
    int tt = p/20, sp = p - tt*20;
    float4 v;
    v.x = pbuf[tt*21 + sp];   v.y = pbuf[tt*21 + sp+1];
    v.z = pbuf[tt*21 + sp+2]; v.w = pbuf[tt*21 + sp+3];
    *(float4*)(out + (size_t)t0c*SUB + p) = v;
  }
}

extern "C" void kernel_launch(void* const* d_in, const int* in_sizes, int n_in,
                              void* d_out, int out_size, void* d_ws, size_t ws_size,
                              hipStream_t stream){
  const float* S_e  = (const float*)d_in[0];
  const float* S_i  = (const float*)d_in[1];
  const float* Z    = (const float*)d_in[2];
  const float* Cden = (const float*)d_in[3];
  const float* C_e  = (const float*)d_in[4];
  const float* C_i  = (const float*)d_in[5];
  const float* Tau  = (const float*)d_in[6];
  const float* Del  = (const float*)d_in[7];
  const float* Wsyn = (const float*)d_in[8];
  const float* Wspk = (const float*)d_in[9];
  const float* Whist= (const float*)d_in[10];
  const float* Theta= (const float*)d_in[11];
  float* out = (float*)d_out;

  // workspace layout (bf16 elements) — identical to R3/R5 passing rounds
  u16* xe    = (u16*)d_ws;
  u16* xi    = xe + (size_t)SUB*T_DATA;
  u16* zt    = xi + (size_t)SUB*T_DATA;
  u16* afrag = zt + (size_t)SUB*T_DATA;            // 4*20*7*512
  u16* bfrag = afrag + (size_t)4*SUB*KKN*512;      // 10240
  size_t need = ((size_t)3*SUB*T_DATA + (size_t)4*SUB*KKN*512 + 10240) * 2;
  if (ws_size < need) return;   // ~60.6 MB required

  k_setup<<<80 + 4*SUB*KKN + 40, 64, 0, stream>>>(
      Tau, Del, Wsyn, Wspk, Whist, C_e, C_i, out, afrag, bfrag);

  k_gather_all<<<3*GBLK, 256, 0, stream>>>(S_e, S_i, Z, bfrag, xe, xi, zt);

  k_conv<<<NCHUNKS_TOT, 512, 0, stream>>>(xe, xi, zt, afrag, Cden, Theta, out);
}

// Round 7
// 267.462 us; speedup vs baseline: 1.4060x; 1.0271x over previous
//
#include <hip/hip_runtime.h>
#include <hip/hip_bf16.h>
#include <math.h>

typedef unsigned int u32;
typedef unsigned short u16;
typedef __bf16 bf16x8 __attribute__((ext_vector_type(8)));
typedef float f32x4 __attribute__((ext_vector_type(4)));
typedef u32 u32x4 __attribute__((ext_vector_type(4)));
typedef u32 u32x2 __attribute__((ext_vector_type(2)));

#define T_DATA 500000
#define KNO    200          // T_no (kernel length)
#define SUB    20
#define E_NO   200
#define I_NO   50
#define NBAS   13
#define PI_F   3.14159265358979f
#define KKN    7            // conv K-tiles: 7*32 = 224 window
#define P_SZ   (T_DATA*SUB) // 10,000,000
#define MT_TOT (T_DATA/16)  // 31250
#define TCH    256
#define NCHUNKS_TOT ((T_DATA + TCH - 1)/TCH)   // 1954
#define GBLK   ((MT_TOT + 3)/4)                // 7813
#define PRT    (NCHUNKS_TOT*TCH)               // 500224 padded partial-row stride

__device__ __forceinline__ float bf2f(u16 v){
  union { u32 u; float f; } x; x.u = ((u32)v) << 16; return x.f;
}
__device__ __forceinline__ u16 f2bf(float f){
  union { float f; u32 u; } x; x.f = f;
  u32 u = x.u;
  return (u16)((u + 0x7FFFu + ((u >> 16) & 1u)) >> 16);
}
__device__ __forceinline__ u16 trunc_bf(float f){   // exact for 0.0/1.0 spikes
  union { float f; u32 u; } x; x.f = f;
  return (u16)(x.u >> 16);
}
__device__ __forceinline__ u32 f2u(float f){
  union { float f; u32 u; } x; x.f = f; return x.u;
}

// kernel-bank value k_{type,s}[j];  type: 0=e,1=i,2=spk,3=hist   (all params f32)
__device__ __forceinline__ float filt_val(int type, int s, int j,
    const float* Tau, const float* Del, const float* Wsyn,
    const float* Wspk, const float* Whist){
  if (type < 2){
    float tau = Tau[s*2+type];
    float del = Del[s*2+type];
    float w   = Wsyn[s*2+type];
    float t   = fmaxf((float)j - del, 0.0f);
    float tt  = t / (tau*tau);
    float v   = tt * expf(-tt) * (w*w);
    return (type == 1) ? -v : v;
  } else {
    const float* W = (type == 2) ? Wspk : Whist;
    float raw = 3.0f * logf((float)j + 1.0f);
    float acc = 0.0f;
#pragma unroll
    for (int b = 0; b < NBAS; b++){
      float d = raw - 0.5f*PI_F*(float)b;
      float bas = (d >= -PI_F && d <= PI_F) ? (0.5f*cosf(d) + 0.5f) : 0.0f;
      acc += W[s*NBAS + b] * bas;
    }
    return acc;
  }
}

// ---- K0 merged setup: filters tail (blocks 0..79), afrag (80..639), bfrag (640..679) ----
__global__ void k_setup(const float* Tau, const float* Del, const float* Wsyn,
                        const float* Wspk, const float* Whist,
                        const float* Ce, const float* Ci,
                        float* out, u16* afrag, u16* bfrag){
  int bid = blockIdx.x;
  int tid = threadIdx.x;
  if (bid < 80){
    int r = bid, type = r / SUB, s = r % SUB;
    for (int j = tid; j < KNO; j += 64)
      out[P_SZ + r*KNO + j] = filt_val(type, s, j, Tau, Del, Wsyn, Wspk, Whist);
  } else if (bid < 80 + 4*SUB*KKN){
    int b = bid - 80;
    int kk = b % KKN;
    int ts = b / KKN;
    int type = ts / SUB, s = ts % SUB;
    __shared__ float kf[KNO];
    for (int j = tid; j < KNO; j += 64)
      kf[j] = filt_val(type, s, j, Tau, Del, Wsyn, Wspk, Whist);
    __syncthreads();
    int l = tid;
    int m = l & 15, kg = l >> 4;
    int off = 200 - 32*kk;
    u32 p[4];
#pragma unroll
    for (int h = 0; h < 4; h++){
      int u0 = kg*8 + 2*h;
      int i0 = off + m - 1 - u0;
      int i1 = i0 - 1;
      u16 lo = (i0 >= 0 && i0 < KNO) ? f2bf(kf[i0]) : (u16)0;
      u16 hi = (i1 >= 0 && i1 < KNO) ? f2bf(kf[i1]) : (u16)0;
      p[h] = (u32)lo | ((u32)hi << 16);
    }
    u32* dst = (u32*)(afrag + (size_t)b*512 + l*8);
    dst[0]=p[0]; dst[1]=p[1]; dst[2]=p[2]; dst[3]=p[3];
  } else {
    const int NE = 2*7*512, NI = 2*2*512, NZ = 2*1*512;
    int b = bid - (80 + 4*SUB*KKN);               // 0..39
    for (int x = b*64 + tid; x < NE+NI+NZ; x += 40*64){
      int src, base, KT;
      if (x < NE){ src=0; base=x;       KT=7; }
      else if (x < NE+NI){ src=1; base=x-NE;    KT=2; }
      else {               src=2; base=x-NE-NI; KT=1; }
      int nt = base / (KT*512);
      int rem = base % (KT*512);
      int kt = rem / 512;
      int le = rem % 512;
      int l = le / 8, e = le % 8;
      int n = nt*16 + (l & 15);
      int k = kt*32 + (l >> 4)*8 + e;
      u16 v = 0;
      if (src == 0){ if (n < SUB && k < E_NO) v = trunc_bf(Ce[n*E_NO + k]); }
      else if (src == 1){ if (n < SUB && k < I_NO) v = trunc_bf(Ci[n*I_NO + k]); }
      else { if (n < SUB && k == n) v = trunc_bf(1.0f); }
      bfrag[x] = v;
    }
  }
}

// ---- K1: gather via MFMA with HOISTED loads: dst[s][t] = sum_k src[t][k]*B[k][s] ----
template<int W, int KT>
__device__ __forceinline__ void gather_body(int bid, const float* __restrict__ src,
                                            const u16* __restrict__ bfrag,
                                            u16* __restrict__ dst){
  int wv = threadIdx.x >> 6, lane = threadIdx.x & 63;
  int mt = bid*4 + wv;
  if (mt >= MT_TOT) return;
  int t0 = mt*16;
  int m = lane & 15, kg = lane >> 4;
  const size_t NW = (size_t)T_DATA * W;

  u32 wb[KT][8];
#pragma unroll
  for (int kt = 0; kt < KT; kt++){
    size_t cs = (size_t)(t0 + m)*W + kt*32 + kg*8;
    if (cs + 8 <= NW){
      if (W == 50){                        // rows only 8B-aligned
        *(u32x2*)&wb[kt][0] = *(const u32x2*)(src + cs);
        *(u32x2*)&wb[kt][2] = *(const u32x2*)(src + cs + 2);
        *(u32x2*)&wb[kt][4] = *(const u32x2*)(src + cs + 4);
        *(u32x2*)&wb[kt][6] = *(const u32x2*)(src + cs + 6);
      } else {                             // 16B-aligned (W=200, W=20)
        *(u32x4*)&wb[kt][0] = *(const u32x4*)(src + cs);
        *(u32x4*)&wb[kt][4] = *(const u32x4*)(src + cs + 4);
      }
    } else {
#pragma unroll
      for (int e = 0; e < 8; e++){
        size_t idx = cs + e;
        wb[kt][e] = (idx < NW) ? f2u(src[idx]) : 0u;
      }
    }
  }

  f32x4 acc0 = {0.f,0.f,0.f,0.f}, acc1 = {0.f,0.f,0.f,0.f};
#pragma unroll
  for (int kt = 0; kt < KT; kt++){
    union { bf16x8 v; u16 h[8]; } au;
#pragma unroll
    for (int e = 0; e < 8; e++) au.h[e] = (u16)(wb[kt][e] >> 16);
    bf16x8 b0 = *(const bf16x8*)(bfrag + kt*512 + lane*8);
    bf16x8 b1 = *(const bf16x8*)(bfrag + (KT + kt)*512 + lane*8);
    acc0 = __builtin_amdgcn_mfma_f32_16x16x32_bf16(au.v, b0, acc0, 0, 0, 0);
    acc1 = __builtin_amdgcn_mfma_f32_16x16x32_bf16(au.v, b1, acc1, 0, 0, 0);
  }
  int i0 = kg*4;   // C/D: t = 16*(lane&15) + 4*kg + reg ; channel = row block
  {
    u32 lo = (u32)f2bf(acc0[0]) | ((u32)f2bf(acc0[1]) << 16);
    u32 hi = (u32)f2bf(acc0[2]) | ((u32)f2bf(acc0[3]) << 16);
    u32* d = (u32*)(dst + (size_t)m*T_DATA + t0 + i0);
    d[0] = lo; d[1] = hi;
  }
  if (m < SUB - 16){
    u32 lo = (u32)f2bf(acc1[0]) | ((u32)f2bf(acc1[1]) << 16);
    u32 hi = (u32)f2bf(acc1[2]) | ((u32)f2bf(acc1[3]) << 16);
    u32* d = (u32*)(dst + (size_t)(16 + m)*T_DATA + t0 + i0);
    d[0] = lo; d[1] = hi;
  }
}

__global__ __launch_bounds__(256, 4) void k_gather_all(
    const float* __restrict__ S_e, const float* __restrict__ S_i,
    const float* __restrict__ Z, const u16* __restrict__ bfrag,
    u16* __restrict__ xe, u16* __restrict__ xi, u16* __restrict__ zt){
  int bid = blockIdx.x;
  if (bid < GBLK)            gather_body<200,7>(bid,          S_e, bfrag,                       xe);
  else if (bid < 2*GBLK)     gather_body<50, 2>(bid - GBLK,   S_i, bfrag + 2*7*512,             xi);
  else                       gather_body<20, 1>(bid - 2*GBLK, Z,   bfrag + 2*7*512 + 2*2*512,   zt);
}

// ---- shared load helper ----
template<bool G>
__device__ __forceinline__ bf16x8 loadw(const u16* __restrict__ row, long base){
  if (!G) return *(const bf16x8*)(row + base);
  union { bf16x8 v; u16 h[8]; } u;
#pragma unroll
  for (int e = 0; e < 8; e++){
    long idx = base + e;
    u.h[e] = (idx >= 0 && idx < T_DATA) ? row[idx] : (u16)0;
  }
  return u.v;
}

// ---- K2a: conv partials. grid = 3*NCHUNKS: type 0=e,1=i,2=z(spk+hist) ----
// pr rows: [0,20)=syn_e, [20,40)=syn_i, [40,60)=spk, [60,80)=hist; stride PRT (padded)
template<bool G>
__device__ __forceinline__ void convp_body(int type, int wv, int lane, int c,
    const u16* __restrict__ xe, const u16* __restrict__ xi,
    const u16* __restrict__ zt, const u16* __restrict__ afrag,
    u16* __restrict__ pr)
{
  int m = lane & 15, kg = lane >> 4;
  int boffB = 16*m + 8*kg;
  int toff  = 16*m + 4*kg;
  long wbase = (long)c*TCH - 200 + boffB;
  int ch0 = wv*5;

  if (type < 2){
    const u16* xs = (type == 0) ? xe : xi;
#pragma unroll
    for (int q = 0; q < 5; q++){
      int ch = ch0 + q;
      const u16* row = xs + (size_t)ch*T_DATA;
      const u16* aa  = afrag + (size_t)((type*SUB + ch)*KKN)*512 + lane*8;
      bf16x8 b[KKN];
#pragma unroll
      for (int kk = 0; kk < KKN; kk++) b[kk] = loadw<G>(row, wbase + 32*kk);
      f32x4 a = {0.f,0.f,0.f,0.f};
#pragma unroll
      for (int kk = 0; kk < KKN; kk++)
        a = __builtin_amdgcn_mfma_f32_16x16x32_bf16(*(const bf16x8*)(aa + kk*512), b[kk], a, 0,0,0);
      u32* d = (u32*)(pr + (size_t)(type*SUB + ch)*PRT + (size_t)c*TCH + toff);
      d[0] = (u32)f2bf(a[0]) | ((u32)f2bf(a[1]) << 16);
      d[1] = (u32)f2bf(a[2]) | ((u32)f2bf(a[3]) << 16);
    }
  } else {
#pragma unroll
    for (int q = 0; q < 5; q++){
      int ch = ch0 + q;
      const u16* row = zt + (size_t)ch*T_DATA;
      const u16* a2  = afrag + (size_t)((2*SUB + ch)*KKN)*512 + lane*8;
      const u16* a3  = afrag + (size_t)((3*SUB + ch)*KKN)*512 + lane*8;
      bf16x8 b[KKN];
#pragma unroll
      for (int kk = 0; kk < KKN; kk++) b[kk] = loadw<G>(row, wbase + 32*kk);
      f32x4 s = {0.f,0.f,0.f,0.f}, h = {0.f,0.f,0.f,0.f};
#pragma unroll
      for (int kk = 0; kk < KKN; kk++){
        s = __builtin_amdgcn_mfma_f32_16x16x32_bf16(*(const bf16x8*)(a2 + kk*512), b[kk], s, 0,0,0);
        h = __builtin_amdgcn_mfma_f32_16x16x32_bf16(*(const bf16x8*)(a3 + kk*512), b[kk], h, 0,0,0);
      }
      u32* d1 = (u32*)(pr + (size_t)(2*SUB + ch)*PRT + (size_t)c*TCH + toff);
      d1[0] = (u32)f2bf(s[0]) | ((u32)f2bf(s[1]) << 16);
      d1[1] = (u32)f2bf(s[2]) | ((u32)f2bf(s[3]) << 16);
      u32* d2 = (u32*)(pr + (size_t)(3*SUB + ch)*PRT + (size_t)c*TCH + toff);
      d2[0] = (u32)f2bf(h[0]) | ((u32)f2bf(h[1]) << 16);
      d2[1] = (u32)f2bf(h[2]) | ((u32)f2bf(h[3]) << 16);
    }
  }
}

__global__ __launch_bounds__(256, 4) void k_convp(
    const u16* __restrict__ xe, const u16* __restrict__ xi,
    const u16* __restrict__ zt, const u16* __restrict__ afrag,
    u16* __restrict__ pr)
{
  int bid = blockIdx.x;
  int type = bid / NCHUNKS_TOT;
  int cb = bid - type*NCHUNKS_TOT;
  // bijective XCD-aware chunk swizzle within each type
  int xcd = cb & 7, sb = cb >> 3;
  const int q8 = NCHUNKS_TOT >> 3, r8 = NCHUNKS_TOT & 7;   // 244, 2
  int c = (xcd < r8 ? xcd*(q8+1) : r8*(q8+1) + (xcd-r8)*q8) + sb;
  int wv = threadIdx.x >> 6, lane = threadIdx.x & 63;
  if (c > 0 && c < NCHUNKS_TOT-1)
    convp_body<false>(type, wv, lane, c, xe, xi, zt, afrag, pr);
  else
    convp_body<true >(type, wv, lane, c, xe, xi, zt, afrag, pr);
}

// ---- K2b: epilogue: P = sigmoid(syn_e+syn_i + theta + hist + Cden @ spk) ----
#define ETB 512
__global__ __launch_bounds__(512, 4) void k_epi(
    const u16* __restrict__ pr, const float* __restrict__ Cden,
    const float* __restrict__ Theta, float* __restrict__ out)
{
  __shared__ float lcden[SUB*SUB];
  __shared__ float lth[SUB];
  __shared__ float pbuf[ETB*21];

  int tid = threadIdx.x;
  if (tid < SUB*SUB) lcden[tid] = Cden[tid];
  else if (tid < SUB*SUB + SUB) lth[tid - SUB*SUB] = Theta[tid - SUB*SUB];
  __syncthreads();

  long t0 = (long)blockIdx.x * ETB;
  long t  = t0 + tid;
  if (t < T_DATA){
    float spv[SUB];
#pragma unroll
    for (int s = 0; s < SUB; s++) spv[s] = bf2f(pr[(size_t)(2*SUB + s)*PRT + t]);
    float res[SUB];
#pragma unroll
    for (int sp = 0; sp < SUB; sp++){
      float msum = bf2f(pr[(size_t)sp*PRT + t]) + bf2f(pr[(size_t)(SUB + sp)*PRT + t])
                 + lth[sp] + bf2f(pr[(size_t)(3*SUB + sp)*PRT + t]);
#pragma unroll
      for (int u = 0; u < SUB; u++) msum += lcden[sp*SUB + u] * spv[u];
      res[sp] = 1.0f/(1.0f + expf(-msum));
    }
#pragma unroll
    for (int sp = 0; sp < SUB; sp++) pbuf[tid*21 + sp] = res[sp];
  }
  __syncthreads();

  int tv = (int)min((long)ETB, (long)(T_DATA - t0));
  if (tv > 0){
    int np4 = tv*SUB/4;
    for (int i = tid; i < np4; i += ETB){
      int p = i*4;
      int tt = p/20, sp = p - tt*20;
      float4 v;
      v.x = pbuf[tt*21 + sp];   v.y = pbuf[tt*21 + sp+1];
      v.z = pbuf[tt*21 + sp+2]; v.w = pbuf[tt*21 + sp+3];
      *(float4*)(out + (size_t)t0*SUB + p) = v;
    }
  }
}

// ---- FALLBACK (R6 fused conv) if ws is too small for partials ----
template<bool G>
__device__ __forceinline__ void conv_mfma(int wv, int lane, int c,
    const u16* __restrict__ xe, const u16* __restrict__ xi,
    const u16* __restrict__ zt, const u16* __restrict__ afrag, u16* rr)
{
  int m = lane & 15, kg = lane >> 4;
  int boffB = 16*m + 8*kg;
  int toff  = 16*m + 4*kg;
  long wbase = (long)c*TCH - 200 + boffB;

  if (wv < 4){
    int ch0 = wv*5;
    f32x4 acc[5];
#pragma unroll
    for (int q = 0; q < 5; q++){
      int ch = ch0 + q;
      const u16* rowE = xe + (size_t)ch*T_DATA;
      const u16* rowI = xi + (size_t)ch*T_DATA;
      const u16* ae = afrag + (size_t)((0*SUB + ch)*KKN)*512 + lane*8;
      const u16* ai = afrag + (size_t)((1*SUB + ch)*KKN)*512 + lane*8;
      bf16x8 be[KKN], bi[KKN];
#pragma unroll
      for (int kk = 0; kk < KKN; kk++) be[kk] = loadw<G>(rowE, wbase + 32*kk);
#pragma unroll
      for (int kk = 0; kk < KKN; kk++) bi[kk] = loadw<G>(rowI, wbase + 32*kk);
      f32x4 a = {0.f,0.f,0.f,0.f};
#pragma unroll
      for (int kk = 0; kk < KKN; kk++){
        a = __builtin_amdgcn_mfma_f32_16x16x32_bf16(*(const bf16x8*)(ae + kk*512), be[kk], a, 0,0,0);
        a = __builtin_amdgcn_mfma_f32_16x16x32_bf16(*(const bf16x8*)(ai + kk*512), bi[kk], a, 0,0,0);
      }
      acc[q] = a;
    }
#pragma unroll
    for (int q = 0; q < 5; q++){
      int ch = ch0 + q;
      u32* d = (u32*)(rr + ch*TCH + toff);
      d[0] = (u32)f2bf(acc[q][0]) | ((u32)f2bf(acc[q][1]) << 16);
      d[1] = (u32)f2bf(acc[q][2]) | ((u32)f2bf(acc[q][3]) << 16);
    }
  } else {
    int ch0 = (wv - 4)*5;
    f32x4 as[5], ah[5];
#pragma unroll
    for (int q = 0; q < 5; q++){
      int ch = ch0 + q;
      const u16* rowZ = zt + (size_t)ch*T_DATA;
      const u16* a2 = afrag + (size_t)((2*SUB + ch)*KKN)*512 + lane*8;
      const u16* a3 = afrag + (size_t)((3*SUB + ch)*KKN)*512 + lane*8;
      bf16x8 bz[KKN];
#pragma unroll
      for (int kk = 0; kk < KKN; kk++) bz[kk] = loadw<G>(rowZ, wbase + 32*kk);
      f32x4 s = {0.f,0.f,0.f,0.f}, h = {0.f,0.f,0.f,0.f};
#pragma unroll
      for (int kk = 0; kk < KKN; kk++){
        s = __builtin_amdgcn_mfma_f32_16x16x32_bf16(*(const bf16x8*)(a2 + kk*512), bz[kk], s, 0,0,0);
        h = __builtin_amdgcn_mfma_f32_16x16x32_bf16(*(const bf16x8*)(a3 + kk*512), bz[kk], h, 0,0,0);
      }
      as[q] = s; ah[q] = h;
    }
#pragma unroll
    for (int q = 0; q < 5; q++){
      int ch = ch0 + q;
      u32* d1 = (u32*)(rr + (SUB + ch)*TCH + toff);
      d1[0] = (u32)f2bf(as[q][0]) | ((u32)f2bf(as[q][1]) << 16);
      d1[1] = (u32)f2bf(as[q][2]) | ((u32)f2bf(as[q][3]) << 16);
      u32* d2 = (u32*)(rr + (2*SUB + ch)*TCH + toff);
      d2[0] = (u32)f2bf(ah[q][0]) | ((u32)f2bf(ah[q][1]) << 16);
      d2[1] = (u32)f2bf(ah[q][2]) | ((u32)f2bf(ah[q][3]) << 16);
    }
  }
}

__global__ __launch_bounds__(512, 4) void k_conv(
    const u16* __restrict__ xe, const u16* __restrict__ xi,
    const u16* __restrict__ zt, const u16* __restrict__ afrag,
    const float* __restrict__ Cden, const float* __restrict__ Theta,
    float* __restrict__ out)
{
  __shared__ __align__(16) u16 rr[3*SUB*TCH];
  __shared__ float lcden[SUB*SUB];
  __shared__ float lth[SUB];
  float* pbuf = (float*)rr;

  int tid = threadIdx.x;
  if (tid < SUB*SUB) lcden[tid] = Cden[tid];
  else if (tid < SUB*SUB + SUB) lth[tid - SUB*SUB] = Theta[tid - SUB*SUB];

  int bid = blockIdx.x;
  int xcd = bid & 7, sb = bid >> 3;
  const int q8 = NCHUNKS_TOT >> 3, r8 = NCHUNKS_TOT & 7;
  int c = (xcd < r8 ? xcd*(q8+1) : r8*(q8+1) + (xcd-r8)*q8) + sb;

  int wv = tid >> 6, lane = tid & 63;
  if (c > 0 && c < NCHUNKS_TOT-1)
    conv_mfma<false>(wv, lane, c, xe, xi, zt, afrag, rr);
  else
    conv_mfma<true >(wv, lane, c, xe, xi, zt, afrag, rr);
  __syncthreads();

  int t = tid >> 1, h = tid & 1;
  float spkv[SUB];
#pragma unroll
  for (int s = 0; s < SUB; s++) spkv[s] = bf2f(rr[(SUB + s)*TCH + t]);
  float res[10];
#pragma unroll
  for (int j = 0; j < 10; j++){
    int sp = h*10 + j;
    float msum = bf2f(rr[sp*TCH + t]) + lth[sp] + bf2f(rr[(2*SUB + sp)*TCH + t]);
#pragma unroll
    for (int s = 0; s < SUB; s++) msum += lcden[sp*SUB + s] * spkv[s];
    res[j] = 1.0f/(1.0f + expf(-msum));
  }
  __syncthreads();
#pragma unroll
  for (int j = 0; j < 10; j++) pbuf[t*21 + h*10 + j] = res[j];
  __syncthreads();

  int t0c = c*TCH;
  int tv = min(TCH, T_DATA - t0c);
  int np4 = tv*SUB/4;
  for (int i = tid; i < np4; i += 512){
    int p = i*4;
    int tt = p/20, sp = p - tt*20;
    float4 v;
    v.x = pbuf[tt*21 + sp];   v.y = pbuf[tt*21 + sp+1];
    v.z = pbuf[tt*21 + sp+2]; v.w = pbuf[tt*21 + sp+3];
    *(float4*)(out + (size_t)t0c*SUB + p) = v;
  }
}

extern "C" void kernel_launch(void* const* d_in, const int* in_sizes, int n_in,
                              void* d_out, int out_size, void* d_ws, size_t ws_size,
                              hipStream_t stream){
  const float* S_e  = (const float*)d_in[0];
  const float* S_i  = (const float*)d_in[1];
  const float* Z    = (const float*)d_in[2];
  const float* Cden = (const float*)d_in[3];
  const float* C_e  = (const float*)d_in[4];
  const float* C_i  = (const float*)d_in[5];
  const float* Tau  = (const float*)d_in[6];
  const float* Del  = (const float*)d_in[7];
  const float* Wsyn = (const float*)d_in[8];
  const float* Wspk = (const float*)d_in[9];
  const float* Whist= (const float*)d_in[10];
  const float* Theta= (const float*)d_in[11];
  float* out = (float*)d_out;

  // workspace layout (bf16 elements); prefix identical to R6 passing round
  u16* xe    = (u16*)d_ws;
  u16* xi    = xe + (size_t)SUB*T_DATA;
  u16* zt    = xi + (size_t)SUB*T_DATA;
  u16* afrag = zt + (size_t)SUB*T_DATA;            // 4*20*7*512 = 286720
  u16* bfrag = afrag + (size_t)4*SUB*KKN*512;      // 10240
  u16* pr    = bfrag + 10240;                      // 80 * PRT partial rows
  size_t need_old = ((size_t)3*SUB*T_DATA + (size_t)4*SUB*KKN*512 + 10240) * 2;
  size_t need_new = need_old + (size_t)4*SUB*PRT*2;
  if (ws_size < need_old) return;   // ~60.6 MB minimum

  k_setup<<<80 + 4*SUB*KKN + 40, 64, 0, stream>>>(
      Tau, Del, Wsyn, Wspk, Whist, C_e, C_i, out, afrag, bfrag);

  k_gather_all<<<3*GBLK, 256, 0, stream>>>(S_e, S_i, Z, bfrag, xe, xi, zt);

  if (ws_size >= need_new){
    k_convp<<<3*NCHUNKS_TOT, 256, 0, stream>>>(xe, xi, zt, afrag, pr);
    k_epi<<<(T_DATA + ETB - 1)/ETB, ETB, 0, stream>>>(pr, Cden, Theta, out);
  } else {
    k_conv<<<NCHUNKS_TOT, 512, 0, stream>>>(xe, xi, zt, afrag, Cden, Theta, out);
  }
}